// Round 1
// baseline (466.823 us; speedup 1.0000x reference)
//
#include <hip/hip_runtime.h>

// PostNormBoth: T=256-step recurrence, B=512 independent chains, H=256.
// Design: 256 blocks x 512 threads; each block owns 2 batch rows end-to-end.
//  - W_update held as bf16 MFMA A-fragments in VGPRs (64 VGPR/lane, 8 waves
//    cover all 256 rows of W) -> zero per-step W traffic.
//  - per-row memory[64][256] f32 in LDS (128KB), h kept in registers,
//    GEMM via v_mfma_f32_16x16x32_bf16 with N=16 (2 real cols, rest zero).
//  - 3 __syncthreads per step; scatter(t)+gather(t+1) fused (column-exclusive).

#define TT 256

typedef __bf16 bf16x8 __attribute__((ext_vector_type(8)));
typedef float  f32x4  __attribute__((ext_vector_type(4)));

__device__ __forceinline__ float fast_tanh(float x) {
    // tanh(x) = 1 - 2/(e^{2x}+1); exact at +/-inf, ~1e-6 rel err.
    float e = __expf(2.f * x);
    return 1.f - __fdividef(2.f, e + 1.f);
}

// ---- dynamic LDS layout (bytes) ----
// s_mem  [2][64][256] f32 :      0  (131072)
// s_x    [2][256]     f32 : 131072  (2048)
// s_y    [2][256]     f32 : 133120  (2048)
// s_v    [2][264]     bf16: 135168  (1056)
// s_red  [8][2]       f32 : 136224  (64)
// s_wt   [64][5]      f32 : 136288  (1280)
// s_it   [64][5]      i32 : 137568  (1280)
// s_oacc [20]         f32 : 138848  (80)
// total                   : 138928
#define SMEM_BYTES 138928

__global__ __launch_bounds__(512, 2)
void postnorm_kernel(const float* __restrict__ x,
                     const float* __restrict__ W_embed,
                     const float* __restrict__ b_embed,
                     const float* __restrict__ W_update,
                     const float* __restrict__ b_update,
                     const float* __restrict__ gamma,
                     const float* __restrict__ beta,
                     const float* __restrict__ W_out,
                     const float* __restrict__ b_out,
                     const float* __restrict__ ctx_s,
                     float* __restrict__ out)
{
    extern __shared__ __align__(16) char smem[];
    float*  s_mem  = (float*)(smem);
    float*  s_x    = (float*)(smem + 131072);
    float*  s_y    = (float*)(smem + 133120);
    __bf16* s_v    = (__bf16*)(smem + 135168);
    float*  s_red  = (float*)(smem + 136224);
    float*  s_wt   = (float*)(smem + 136288);
    int*    s_it   = (int*)  (smem + 137568);
    float*  s_oacc = (float*)(smem + 138848);

    const int tid  = threadIdx.x;
    const int n    = tid >> 8;      // batch row within block (0..1)
    const int i    = tid & 255;     // hidden index
    const int wave = tid >> 6;      // 0..7, wave w owns W rows [32w,32w+32)
    const int lane = tid & 63;
    const int bn   = lane & 15;     // MFMA col (batch slot); real only for <2
    const int quad = lane >> 4;
    const int r0   = blockIdx.x * 2;

    // ---- init ----
    {   // zero memory (131072 B)
        f32x4 z = {0.f, 0.f, 0.f, 0.f};
        f32x4* p = (f32x4*)s_mem;
        #pragma unroll
        for (int k = 0; k < 16; ++k) p[tid + k * 512] = z;
    }
    if (tid < 264) ((unsigned int*)s_v)[tid] = 0u;   // zero vbuf (incl pad)
    s_x[tid] = x[(r0 + n) * TT + i];                 // stage x rows
    if (tid < 20) s_oacc[tid] = 0.f;

    // attention tables: pointer is t&63 for all rows -> 64-entry table
    if (tid < 64) {
        float wv[5]; float ssum = 0.f;
        #pragma unroll
        for (int k = 0; k < 5; ++k) {
            int idx = (tid + k - 2) & 63;            // (base+off) mod 64
            float d = (float)idx - (float)tid;       // delta AFTER wrap
            wv[k] = expf(-(d * d) * 0.125f);         // TAU=8 -> *0.125 exact
            ssum += wv[k];
            s_it[tid * 5 + k] = idx;
        }
        #pragma unroll
        for (int k = 0; k < 5; ++k) s_wt[tid * 5 + k] = wv[k] / ssum;
    }

    // per-thread params for the (n,i) role
    const float we  = W_embed[i];
    const float be  = b_embed[i];
    const float bu  = b_update[i];
    const float gm  = gamma[i];
    const float btt = beta[i];
    const float csv = 1.f / (1.f + expf(-ctx_s[0]));  // sigmoid once

    // ---- W_update -> bf16 A-fragments, resident in VGPRs ----
    // A[m][k] = W[j0+m][k0+k]; lane: m=bn, k0=quad*8, element e -> k0+e.
    bf16x8 wfa[2][8];
    #pragma unroll
    for (int mt = 0; mt < 2; ++mt) {
        #pragma unroll
        for (int kt = 0; kt < 8; ++kt) {
            const float* wp = W_update + (wave * 32 + mt * 16 + bn) * 256
                                       + kt * 32 + quad * 8;
            f32x4 a = *(const f32x4*)wp;
            f32x4 b = *(const f32x4*)(wp + 4);
            bf16x8 f;
            f[0] = (__bf16)a[0]; f[1] = (__bf16)a[1];
            f[2] = (__bf16)a[2]; f[3] = (__bf16)a[3];
            f[4] = (__bf16)b[0]; f[5] = (__bf16)b[1];
            f[6] = (__bf16)b[2]; f[7] = (__bf16)b[3];
            wfa[mt][kt] = f;
        }
    }

    __syncthreads();
    // v(t=0): memory==0, h==0 -> v = inp
    {
        float inp = fast_tanh(s_x[n * 256 + 0] * we + be);
        s_v[n * 264 + i] = (__bf16)inp;
    }
    __syncthreads();

    float hn = 0.f;                                   // h[n][i] lives here
    const __bf16* vsrc = s_v + bn * 264 + quad * 8;   // B-frag base (bn<2 only)

    #pragma unroll 1
    for (int t = 0; t < TT; ++t) {
        // --- P1: GEMM y[j,n] = sum_i W[j,i] v[n,i] ---
        f32x4 acc0 = {0.f, 0.f, 0.f, 0.f};
        f32x4 acc1 = {0.f, 0.f, 0.f, 0.f};
        #pragma unroll
        for (int kt = 0; kt < 8; ++kt) {
            bf16x8 bfr;
            #pragma unroll
            for (int z = 0; z < 8; ++z) bfr[z] = (__bf16)0.f;
            if (bn < 2) bfr = *(const bf16x8*)(vsrc + kt * 32);
            acc0 = __builtin_amdgcn_mfma_f32_16x16x32_bf16(wfa[0][kt], bfr, acc0, 0, 0, 0);
            acc1 = __builtin_amdgcn_mfma_f32_16x16x32_bf16(wfa[1][kt], bfr, acc1, 0, 0, 0);
        }
        if (bn < 2) {                 // D: row = quad*4+reg, col = bn
            float* yb = s_y + bn * 256 + wave * 32 + quad * 4;
            yb[0]  = acc0[0]; yb[1]  = acc0[1]; yb[2]  = acc0[2]; yb[3]  = acc0[3];
            yb[16] = acc1[0]; yb[17] = acc1[1]; yb[18] = acc1[2]; yb[19] = acc1[3];
        }
        __syncthreads();

        // --- P2: bias + tanh + LN partial stats (thread = (n,i)) ---
        float yt = fast_tanh(s_y[tid] + bu);
        float s1 = yt, s2 = yt * yt;
        #pragma unroll
        for (int m = 32; m >= 1; m >>= 1) {
            s1 += __shfl_xor(s1, m, 64);
            s2 += __shfl_xor(s2, m, 64);
        }
        if (lane == 0) { s_red[wave * 2] = s1; s_red[wave * 2 + 1] = s2; }
        __syncthreads();

        // --- P3: LN finalize, scatter(t), gather(t+1), build v(t+1) ---
        float S1 = 0.f, S2 = 0.f;
        #pragma unroll
        for (int ww = 0; ww < 4; ++ww) {
            S1 += s_red[(n * 4 + ww) * 2];
            S2 += s_red[(n * 4 + ww) * 2 + 1];
        }
        float mu   = S1 * (1.f / 256.f);
        float var  = S2 * (1.f / 256.f) - mu * mu;
        float rstd = rsqrtf(var + 1e-5f);
        hn = (yt - mu) * rstd * gm + btt;

        {   // column (n,i) of memory is exclusively ours -> no extra barrier
            const int p5 = (t & 63) * 5;
            float* mcol = s_mem + (n << 14) + i;
            #pragma unroll
            for (int k = 0; k < 5; ++k)
                mcol[s_it[p5 + k] << 8] += s_wt[p5 + k] * hn;

            if (t < TT - 1) {
                const int q5 = ((t + 1) & 63) * 5;
                float ctx = 0.f;
                #pragma unroll
                for (int k = 0; k < 5; ++k)
                    ctx += s_wt[q5 + k] * mcol[s_it[q5 + k] << 8];
                float inp = fast_tanh(s_x[n * 256 + t + 1] * we + be);
                float v = inp + csv * ctx + hn;
                s_v[n * 264 + i] = (__bf16)v;
            }
        }
        __syncthreads();
    }

    // --- epilogue: out[r0+n, o] = h . W_out[o,:] + b_out[o] ---
    #pragma unroll
    for (int o = 0; o < 10; ++o) {
        float p = hn * W_out[o * 256 + i];
        #pragma unroll
        for (int m = 32; m >= 1; m >>= 1) p += __shfl_xor(p, m, 64);
        if (lane == 0) atomicAdd(&s_oacc[n * 10 + o], p);
    }
    __syncthreads();
    if (tid < 20) {
        int nn = tid / 10, o = tid % 10;
        out[(r0 + nn) * 10 + o] = s_oacc[tid] + b_out[o];
    }
}

extern "C" void kernel_launch(void* const* d_in, const int* in_sizes, int n_in,
                              void* d_out, int out_size, void* d_ws, size_t ws_size,
                              hipStream_t stream) {
    const float* x    = (const float*)d_in[0];
    const float* W_e  = (const float*)d_in[1];
    const float* b_e  = (const float*)d_in[2];
    const float* W_u  = (const float*)d_in[3];
    const float* b_u  = (const float*)d_in[4];
    const float* gmm  = (const float*)d_in[5];
    const float* bta  = (const float*)d_in[6];
    const float* W_o  = (const float*)d_in[7];
    const float* b_o  = (const float*)d_in[8];
    const float* cst  = (const float*)d_in[9];
    float* out = (float*)d_out;

    // allow >64KB dynamic LDS (gfx950: 160KB/CU). Host-side, capture-safe.
    (void)hipFuncSetAttribute(reinterpret_cast<const void*>(postnorm_kernel),
                              hipFuncAttributeMaxDynamicSharedMemorySize,
                              SMEM_BYTES);

    postnorm_kernel<<<dim3(256), dim3(512), SMEM_BYTES, stream>>>(
        x, W_e, b_e, W_u, b_u, gmm, bta, W_o, b_o, cst, out);
}

// Round 2
// 319.696 us; speedup vs baseline: 1.4602x; 1.4602x over previous
//
#include <hip/hip_runtime.h>

// PostNormBoth: T=256-step recurrence, B=512 independent chains, H=256.
// R1: sliding-window register memory (5 slots in VGPRs, 2 LDS ops/step),
//     DPP-based LN reduction (no ds_swizzle), vectorized y stores,
//     broadcast B-frag loads, weights carried in registers.

#define TT 256

typedef __bf16 bf16x8 __attribute__((ext_vector_type(8)));
typedef float  f32x4  __attribute__((ext_vector_type(4)));

__device__ __forceinline__ float fast_tanh(float x) {
    float e = __expf(2.f * x);
    return 1.f - __fdividef(2.f, e + 1.f);
}

// v += dpp(v); CTRL/RM compile-time. old=0 + bound_ctrl so masked lanes add 0.
template<int CTRL, int RM>
__device__ __forceinline__ float dpp_add(float v) {
    int t = __builtin_amdgcn_update_dpp(0, __float_as_int(v), CTRL, RM, 0xf, true);
    return v + __int_as_float(t);
}
// full 64-lane sum; valid in lane 63 (rows 48-63).
__device__ __forceinline__ float wave_sum63(float v) {
    v = dpp_add<0xB1,  0xf>(v);   // quad_perm xor1
    v = dpp_add<0x4E,  0xf>(v);   // quad_perm xor2
    v = dpp_add<0x141, 0xf>(v);   // row_half_mirror (8-group)
    v = dpp_add<0x140, 0xf>(v);   // row_mirror (16-group)
    v = dpp_add<0x142, 0xa>(v);   // row_bcast15 -> rows 1,3
    v = dpp_add<0x143, 0xc>(v);   // row_bcast31 -> rows 2,3
    return v;
}

// ---- dynamic LDS layout (bytes) ----
// s_mem  [2][64][256] f32 :      0  (131072)
// s_x    [2][256]     f32 : 131072  (2048)
// s_y    [2][256]     f32 : 133120  (2048)
// s_v    [2][264]     bf16: 135168  (1056)
// s_red1 [8]          f32 : 136224  (32)
// s_red2 [8]          f32 : 136256  (32)
// s_wt   [64][8]      f32 : 136288  (2048)
// s_oacc [20]         f32 : 138336  (80)
#define SMEM_BYTES 138416

__global__ __launch_bounds__(512, 2)
void postnorm_kernel(const float* __restrict__ x,
                     const float* __restrict__ W_embed,
                     const float* __restrict__ b_embed,
                     const float* __restrict__ W_update,
                     const float* __restrict__ b_update,
                     const float* __restrict__ gamma,
                     const float* __restrict__ beta,
                     const float* __restrict__ W_out,
                     const float* __restrict__ b_out,
                     const float* __restrict__ ctx_s,
                     float* __restrict__ out)
{
    extern __shared__ __align__(16) char smem[];
    float*  s_mem  = (float*)(smem);
    float*  s_x    = (float*)(smem + 131072);
    float*  s_y    = (float*)(smem + 133120);
    __bf16* s_v    = (__bf16*)(smem + 135168);
    float*  s_red1 = (float*)(smem + 136224);
    float*  s_red2 = (float*)(smem + 136256);
    float*  s_wt   = (float*)(smem + 136288);
    float*  s_oacc = (float*)(smem + 138336);

    const int tid  = threadIdx.x;
    const int n    = tid >> 8;      // batch row within block (0..1)
    const int i    = tid & 255;     // hidden index
    const int wave = tid >> 6;      // wave w owns W rows [32w,32w+32)
    const int lane = tid & 63;
    const int bn   = lane & 15;     // MFMA col; real batch only for <2
    const int quad = lane >> 4;
    const int r0   = blockIdx.x * 2;

    // ---- init ----
    {   f32x4 z = {0.f, 0.f, 0.f, 0.f};
        f32x4* p = (f32x4*)s_mem;
        #pragma unroll
        for (int k = 0; k < 16; ++k) p[tid + k * 512] = z;
    }
    if (tid < 264) ((unsigned int*)s_v)[tid] = 0u;
    s_x[tid] = x[(r0 + n) * TT + i];
    if (tid < 20) s_oacc[tid] = 0.f;

    // weight table: pointer is t&63 for all rows; row padded to 8 floats
    if (tid < 64) {
        float wv[5]; float ssum = 0.f;
        #pragma unroll
        for (int k = 0; k < 5; ++k) {
            int idx = (tid + k - 2) & 63;            // wrapped index
            float d = (float)idx - (float)tid;       // delta AFTER wrap
            wv[k] = expf(-(d * d) * 0.125f);         // TAU=8
            ssum += wv[k];
        }
        #pragma unroll
        for (int k = 0; k < 5; ++k) s_wt[tid * 8 + k] = wv[k] / ssum;
    }

    const float we  = W_embed[i];
    const float be  = b_embed[i];
    const float bu  = b_update[i];
    const float gm  = gamma[i];
    const float btt = beta[i];
    const float csv = 1.f / (1.f + expf(-ctx_s[0]));

    // ---- W_update -> bf16 MFMA A-fragments resident in VGPRs ----
    bf16x8 wfa[2][8];
    #pragma unroll
    for (int mt = 0; mt < 2; ++mt) {
        #pragma unroll
        for (int kt = 0; kt < 8; ++kt) {
            const float* wp = W_update + (wave * 32 + mt * 16 + bn) * 256
                                       + kt * 32 + quad * 8;
            f32x4 a = *(const f32x4*)wp;
            f32x4 b = *(const f32x4*)(wp + 4);
            bf16x8 f;
            f[0] = (__bf16)a[0]; f[1] = (__bf16)a[1];
            f[2] = (__bf16)a[2]; f[3] = (__bf16)a[3];
            f[4] = (__bf16)b[0]; f[5] = (__bf16)b[1];
            f[6] = (__bf16)b[2]; f[7] = (__bf16)b[3];
            wfa[mt][kt] = f;
        }
    }

    __syncthreads();
    {   // v(t=0): memory==0, h==0 -> v = inp
        float inp = fast_tanh(s_x[n * 256] * we + be);
        s_v[n * 264 + i] = (__bf16)inp;
    }

    // attention weights for pointer 0 (carried in regs)
    float wt0, wt1, wt2, wt3, wt4;
    {   f32x4 wv = *(const f32x4*)(s_wt);
        wt0 = wv[0]; wt1 = wv[1]; wt2 = wv[2]; wt3 = wv[3]; wt4 = s_wt[4];
    }
    __syncthreads();

    float hn = 0.f;
    // register window: slots (t-2..t+2) mod 64 of memory column (n,i)
    float w0 = 0.f, w1 = 0.f, w2 = 0.f, w3 = 0.f, w4 = 0.f;
    float* mcol = s_mem + (n << 14) + i;
    // broadcast B-frag source (columns >=2 of D are never stored -> bn&1 ok)
    const __bf16* vsrc = s_v + (bn & 1) * 264 + quad * 8;

    #pragma unroll 1
    for (int t = 0; t < TT; ++t) {
        // --- P1: y[j,n] = sum_i W[j,i] v[n,i] via MFMA ---
        f32x4 a0a = {0,0,0,0}, a0b = {0,0,0,0}, a1a = {0,0,0,0}, a1b = {0,0,0,0};
        #pragma unroll
        for (int kt = 0; kt < 4; ++kt) {
            bf16x8 bfr0 = *(const bf16x8*)(vsrc + kt * 32);
            bf16x8 bfr1 = *(const bf16x8*)(vsrc + (kt + 4) * 32);
            a0a = __builtin_amdgcn_mfma_f32_16x16x32_bf16(wfa[0][kt],     bfr0, a0a, 0, 0, 0);
            a1a = __builtin_amdgcn_mfma_f32_16x16x32_bf16(wfa[1][kt],     bfr0, a1a, 0, 0, 0);
            a0b = __builtin_amdgcn_mfma_f32_16x16x32_bf16(wfa[0][kt + 4], bfr1, a0b, 0, 0, 0);
            a1b = __builtin_amdgcn_mfma_f32_16x16x32_bf16(wfa[1][kt + 4], bfr1, a1b, 0, 0, 0);
        }
        if (bn < 2) {                 // D: row = quad*4+reg, col = bn
            f32x4 y0 = a0a + a0b, y1 = a1a + a1b;
            float* yb = s_y + bn * 256 + wave * 32 + quad * 4;
            *(f32x4*)yb        = y0;
            *(f32x4*)(yb + 16) = y1;
        }
        __syncthreads();

        // --- P2: bias + tanh + LN stats via DPP ---
        float yt = fast_tanh(s_y[tid] + bu);
        float s1 = wave_sum63(yt);
        float s2 = wave_sum63(yt * yt);
        if (lane == 63) { s_red1[wave] = s1; s_red2[wave] = s2; }
        __syncthreads();

        // --- P3: LN finalize + register-window scatter/gather ---
        f32x4 r1 = *(const f32x4*)(s_red1 + n * 4);
        f32x4 r2 = *(const f32x4*)(s_red2 + n * 4);
        float S1 = (r1[0] + r1[1]) + (r1[2] + r1[3]);
        float S2 = (r2[0] + r2[1]) + (r2[2] + r2[3]);
        float mu   = S1 * (1.f / 256.f);
        float var  = S2 * (1.f / 256.f) - mu * mu;
        float rstd = rsqrtf(var + 1e-5f);
        hn = (yt - mu) * rstd * gm + btt;

        // scatter with pointer-t weights (positional: w0 = slot t-2)
        w0 += wt0 * hn; w1 += wt1 * hn; w2 += wt2 * hn;
        w3 += wt3 * hn; w4 += wt4 * hn;

        if (t < TT - 1) {
            // slide window: retire slot t-2, admit slot t+3
            mcol[((t - 2) & 63) << 8] = w0;
            float nf = mcol[((t + 3) & 63) << 8];
            w0 = w1; w1 = w2; w2 = w3; w3 = w4; w4 = nf;
            // next-step weights
            f32x4 nw = *(const f32x4*)(s_wt + ((t + 1) & 63) * 8);
            float nw4 = s_wt[((t + 1) & 63) * 8 + 4];
            float ctx = ((nw[0] * w0 + nw[1] * w1) + (nw[2] * w2 + nw[3] * w3))
                      + nw4 * w4;
            float inp = fast_tanh(s_x[n * 256 + t + 1] * we + be);
            float v = inp + csv * ctx + hn;
            s_v[n * 264 + i] = (__bf16)v;
            wt0 = nw[0]; wt1 = nw[1]; wt2 = nw[2]; wt3 = nw[3]; wt4 = nw4;
        }
        __syncthreads();
    }

    // --- epilogue: out[r0+n, o] = h . W_out[o,:] + b_out[o] ---
    #pragma unroll
    for (int o = 0; o < 10; ++o) {
        float p = hn * W_out[o * 256 + i];
        #pragma unroll
        for (int m = 32; m >= 1; m >>= 1) p += __shfl_xor(p, m, 64);
        if (lane == 0) atomicAdd(&s_oacc[n * 10 + o], p);
    }
    __syncthreads();
    if (tid < 20) {
        int nn = tid / 10, o = tid % 10;
        out[(r0 + nn) * 10 + o] = s_oacc[tid] + b_out[o];
    }
}

extern "C" void kernel_launch(void* const* d_in, const int* in_sizes, int n_in,
                              void* d_out, int out_size, void* d_ws, size_t ws_size,
                              hipStream_t stream) {
    const float* x    = (const float*)d_in[0];
    const float* W_e  = (const float*)d_in[1];
    const float* b_e  = (const float*)d_in[2];
    const float* W_u  = (const float*)d_in[3];
    const float* b_u  = (const float*)d_in[4];
    const float* gmm  = (const float*)d_in[5];
    const float* bta  = (const float*)d_in[6];
    const float* W_o  = (const float*)d_in[7];
    const float* b_o  = (const float*)d_in[8];
    const float* cst  = (const float*)d_in[9];
    float* out = (float*)d_out;

    (void)hipFuncSetAttribute(reinterpret_cast<const void*>(postnorm_kernel),
                              hipFuncAttributeMaxDynamicSharedMemorySize,
                              SMEM_BYTES);

    postnorm_kernel<<<dim3(256), dim3(512), SMEM_BYTES, stream>>>(
        x, W_e, b_e, W_u, b_u, gmm, bta, W_o, b_o, cst, out);
}